// Round 3
// baseline (152.272 us; speedup 1.0000x reference)
//
#include <hip/hip_runtime.h>
#include <hip/hip_bf16.h>
#include <math.h>

#define B_      8
#define CIN     256
#define CMID    512
#define COUT    256
#define N_      2048
#define SCALE_  10.0f
#define EPS_THR 1e-3f
#define NORM_EPS_ 1e-12f

typedef __attribute__((ext_vector_type(8))) short short8;
typedef __attribute__((ext_vector_type(4))) float f32x4;

__device__ __forceinline__ ushort f2bf(float x) {
    union { float f; uint u; } v; v.f = x;
    uint r = v.u + 0x7FFF + ((v.u >> 16) & 1);
    return (ushort)(r >> 16);
}
__device__ __forceinline__ void gload_lds16(const void* g, void* l) {
    __builtin_amdgcn_global_load_lds((const __attribute__((address_space(1))) void*)g,
                                     (__attribute__((address_space(3))) void*)l, 16, 0, 0);
}

// ---------------- K0: weights fp32 -> bf16 ------------------------------------------
__global__ __launch_bounds__(256) void prep_w(const float* __restrict__ W1,
                                              const float* __restrict__ W2,
                                              ushort* __restrict__ W1b,
                                              ushort* __restrict__ W2b) {
    int idx = blockIdx.x * 256 + threadIdx.x;   // 0..131071
    W1b[idx] = f2bf(W1[idx]);
    W2b[idx] = f2bf(W2[idx]);
}

// ---------------- K1: conv1 fused with input transpose ------------------------------
// H[m][o] = leaky( sum_c x[b][c][n] * W1[o][c] ),  m = (q: b*2048+n | k: 16384+b*2048+n)
// BM=64 rows(m), BN=512 (all outputs), BK=32. 8 waves, wave w -> cols w*64..+63.
#define ASTRIDE 40
__global__ __launch_bounds__(512) void conv1_fused(const float* __restrict__ q,
                                                   const float* __restrict__ k,
                                                   const ushort* __restrict__ W1b,
                                                   ushort* __restrict__ H) {
    __shared__ ushort As[64 * ASTRIDE];   // 5 KB, padded stride
    __shared__ ushort Bs[512 * 32];       // 32 KB
    int tid = threadIdx.x;
    int lane = tid & 63, wave = tid >> 6;
    int g = lane >> 4, cl = lane & 15;
    size_t m0 = (size_t)blockIdx.x * 64;
    const float* xsrc = (m0 < 16384) ? q : k;
    int b = (int)((m0 >> 11) & 7);
    int nbase = (int)(m0 & 2047);
    // staging roles: n_l = lane (column of tile), cg = wave (4-channel group)
    const float* xp = xsrc + ((size_t)b * CIN + wave * 4) * N_ + nbase + lane;

    f32x4 acc[4][4];
#pragma unroll
    for (int i = 0; i < 4; ++i)
#pragma unroll
        for (int j = 0; j < 4; ++j) acc[i][j] = (f32x4)0.f;

    for (int k0 = 0; k0 < CIN; k0 += 32) {
        // B panel: whole W1 rows, gload_lds 4 slots/thread
#pragma unroll
        for (int si = 0; si < 4; ++si) {
            int s = tid + si * 512;
            gload_lds16(W1b + (size_t)(s >> 2) * CIN + k0 + (s & 3) * 8, Bs + s * 8);
        }
        // A tile: 64 n x 32 c, read x coalesced along n, write transposed to LDS
        float v0 = xp[(size_t)(k0 + 0) * N_];
        float v1 = xp[(size_t)(k0 + 1) * N_];
        float v2 = xp[(size_t)(k0 + 2) * N_];
        float v3 = xp[(size_t)(k0 + 3) * N_];
        ushort4 wv;
        wv.x = f2bf(v0); wv.y = f2bf(v1); wv.z = f2bf(v2); wv.w = f2bf(v3);
        *(ushort4*)&As[lane * ASTRIDE + wave * 4] = wv;
        __syncthreads();

        short8 af[4], bfr[4];
#pragma unroll
        for (int mi = 0; mi < 4; ++mi)
            af[mi] = *(const short8*)&As[(mi * 16 + cl) * ASTRIDE + g * 8];
#pragma unroll
        for (int ni = 0; ni < 4; ++ni)
            bfr[ni] = *(const short8*)&Bs[(wave * 64 + ni * 16 + cl) * 32 + g * 8];
#pragma unroll
        for (int mi = 0; mi < 4; ++mi)
#pragma unroll
            for (int ni = 0; ni < 4; ++ni)
                acc[mi][ni] = __builtin_amdgcn_mfma_f32_16x16x32_bf16(af[mi], bfr[ni], acc[mi][ni], 0, 0, 0);
        __syncthreads();
    }

#pragma unroll
    for (int mi = 0; mi < 4; ++mi)
#pragma unroll
        for (int ni = 0; ni < 4; ++ni)
#pragma unroll
            for (int r = 0; r < 4; ++r) {
                float v = acc[mi][ni][r];
                v = (v >= 0.f) ? v : 0.01f * v;
                H[(m0 + mi * 16 + g * 4 + r) * CMID + wave * 64 + ni * 16 + cl] = f2bf(v);
            }
}

// ---------------- K2: conv2 fused with row L2-norm ----------------------------------
// QK[m][o] = Y[m][o]/max(||Y[m]||,eps),  Y = H * W2^T.  BM=128, BN=256(all), BK=32.
__global__ __launch_bounds__(512) void conv2_norm(const ushort* __restrict__ H,
                                                  const ushort* __restrict__ W2b,
                                                  ushort* __restrict__ QK) {
    __shared__ ushort As[128 * 32];   // 8 KB
    __shared__ ushort Bs[256 * 32];   // 16 KB
    __shared__ float red[4][128];     // 2 KB
    int tid = threadIdx.x;
    int lane = tid & 63, wave = tid >> 6;
    int wm = wave >> 2, wn = wave & 3;
    int g = lane >> 4, cl = lane & 15;
    size_t m0 = (size_t)blockIdx.x * 128;

    f32x4 acc[4][4];
#pragma unroll
    for (int i = 0; i < 4; ++i)
#pragma unroll
        for (int j = 0; j < 4; ++j) acc[i][j] = (f32x4)0.f;

    for (int k0 = 0; k0 < CMID; k0 += 32) {
        gload_lds16(H + (m0 + (tid >> 2)) * CMID + k0 + (tid & 3) * 8, As + tid * 8);
#pragma unroll
        for (int si = 0; si < 2; ++si) {
            int s = tid + si * 512;
            gload_lds16(W2b + (size_t)(s >> 2) * CMID + k0 + (s & 3) * 8, Bs + s * 8);
        }
        __syncthreads();
        short8 af[4], bfr[4];
#pragma unroll
        for (int mi = 0; mi < 4; ++mi)
            af[mi] = *(const short8*)&As[(wm * 64 + mi * 16 + cl) * 32 + g * 8];
#pragma unroll
        for (int ni = 0; ni < 4; ++ni)
            bfr[ni] = *(const short8*)&Bs[(wn * 64 + ni * 16 + cl) * 32 + g * 8];
#pragma unroll
        for (int mi = 0; mi < 4; ++mi)
#pragma unroll
            for (int ni = 0; ni < 4; ++ni)
                acc[mi][ni] = __builtin_amdgcn_mfma_f32_16x16x32_bf16(af[mi], bfr[ni], acc[mi][ni], 0, 0, 0);
        __syncthreads();
    }

    // row sum of squares: lane covers rows wm*64+mi*16+g*4+r, cols wn*64+ni*16+cl
#pragma unroll
    for (int mi = 0; mi < 4; ++mi)
#pragma unroll
        for (int r = 0; r < 4; ++r) {
            float s = 0.f;
#pragma unroll
            for (int ni = 0; ni < 4; ++ni) { float v = acc[mi][ni][r]; s += v * v; }
#pragma unroll
            for (int off = 1; off < 16; off <<= 1) s += __shfl_xor(s, off, 64);
            if (cl == 0) red[wn][wm * 64 + mi * 16 + g * 4 + r] = s;
        }
    __syncthreads();
#pragma unroll
    for (int mi = 0; mi < 4; ++mi)
#pragma unroll
        for (int r = 0; r < 4; ++r) {
            int row = wm * 64 + mi * 16 + g * 4 + r;
            float tot = red[0][row] + red[1][row] + red[2][row] + red[3][row];
            float inv = 1.0f / fmaxf(sqrtf(tot), NORM_EPS_);
#pragma unroll
            for (int ni = 0; ni < 4; ++ni)
                QK[(m0 + row) * COUT + wn * 64 + ni * 16 + cl] = f2bf(acc[mi][ni][r] * inv);
        }
}

// ---------------- K3: fused scores*10 + softmax + threshold -------------------------
// Block: 32 q-rows x 2048 k-cols of one batch. 8 waves; wave w -> cols w*256..+255.
__global__ __launch_bounds__(512, 2) void scores_softmax(const ushort* __restrict__ QK,
                                                         float* __restrict__ out) {
    int bid = blockIdx.x;
    int b = bid & 7;                 // batch-per-XCD swizzle (consecutive ids -> XCDs)
    int m0 = (bid >> 3) * 32;
    int tid = threadIdx.x;
    int lane = tid & 63, wave = tid >> 6;
    int g = lane >> 4, cl = lane & 15;

    const ushort* Qb = QK + ((size_t)b * N_ + m0) * COUT;
    const ushort* Kb = QK + ((size_t)16384 + (size_t)b * N_ + wave * 256) * COUT;

    short8 af[2][8];
#pragma unroll
    for (int rt = 0; rt < 2; ++rt)
#pragma unroll
        for (int ks = 0; ks < 8; ++ks)
            af[rt][ks] = *(const short8*)(Qb + (size_t)(rt * 16 + cl) * COUT + ks * 32 + g * 8);

    f32x4 acc[2][16];
#pragma unroll
    for (int rt = 0; rt < 2; ++rt)
#pragma unroll
        for (int ct = 0; ct < 16; ++ct) acc[rt][ct] = (f32x4)0.f;

#pragma unroll
    for (int ct = 0; ct < 16; ++ct)
#pragma unroll
        for (int ks = 0; ks < 8; ++ks) {
            short8 bfr = *(const short8*)(Kb + (size_t)(ct * 16 + cl) * COUT + ks * 32 + g * 8);
            acc[0][ct] = __builtin_amdgcn_mfma_f32_16x16x32_bf16(af[0][ks], bfr, acc[0][ct], 0, 0, 0);
            acc[1][ct] = __builtin_amdgcn_mfma_f32_16x16x32_bf16(af[1][ks], bfr, acc[1][ct], 0, 0, 0);
        }

    // scale by 10
#pragma unroll
    for (int rt = 0; rt < 2; ++rt)
#pragma unroll
        for (int ct = 0; ct < 16; ++ct)
#pragma unroll
            for (int r = 0; r < 4; ++r) acc[rt][ct][r] *= SCALE_;

    __shared__ float red[8][32];
    float gm[2][4];

    // global row max
#pragma unroll
    for (int rt = 0; rt < 2; ++rt)
#pragma unroll
        for (int r = 0; r < 4; ++r) {
            float m = acc[rt][0][r];
#pragma unroll
            for (int ct = 1; ct < 16; ++ct) m = fmaxf(m, acc[rt][ct][r]);
#pragma unroll
            for (int off = 1; off < 16; off <<= 1) m = fmaxf(m, __shfl_xor(m, off, 64));
            if (cl == 0) red[wave][rt * 16 + g * 4 + r] = m;
        }
    __syncthreads();
#pragma unroll
    for (int rt = 0; rt < 2; ++rt)
#pragma unroll
        for (int r = 0; r < 4; ++r) {
            int row = rt * 16 + g * 4 + r;
            float m = red[0][row];
#pragma unroll
            for (int w = 1; w < 8; ++w) m = fmaxf(m, red[w][row]);
            gm[rt][r] = m;
        }
    __syncthreads();

    // exp + global row sum
    float inv[2][4];
#pragma unroll
    for (int rt = 0; rt < 2; ++rt)
#pragma unroll
        for (int r = 0; r < 4; ++r) {
            float s = 0.f;
#pragma unroll
            for (int ct = 0; ct < 16; ++ct) {
                float e = __expf(acc[rt][ct][r] - gm[rt][r]);
                acc[rt][ct][r] = e;
                s += e;
            }
#pragma unroll
            for (int off = 1; off < 16; off <<= 1) s += __shfl_xor(s, off, 64);
            if (cl == 0) red[wave][rt * 16 + g * 4 + r] = s;
        }
    __syncthreads();
#pragma unroll
    for (int rt = 0; rt < 2; ++rt)
#pragma unroll
        for (int r = 0; r < 4; ++r) {
            int row = rt * 16 + g * 4 + r;
            float s = red[0][row];
#pragma unroll
            for (int w = 1; w < 8; ++w) s += red[w][row];
            inv[rt][r] = 1.0f / s;
        }

    float* ob = out + (size_t)b * N_ * N_;
#pragma unroll
    for (int rt = 0; rt < 2; ++rt)
#pragma unroll
        for (int r = 0; r < 4; ++r) {
            size_t rowoff = (size_t)(m0 + rt * 16 + g * 4 + r) * N_;
#pragma unroll
            for (int ct = 0; ct < 16; ++ct) {
                float w = acc[rt][ct][r] * inv[rt][r];
                ob[rowoff + wave * 256 + ct * 16 + cl] = (w > EPS_THR) ? w : 0.f;
            }
        }
}

// ---------------- K4: copy key to output tail ---------------------------------------
__global__ __launch_bounds__(256) void copy_key(const float* __restrict__ in,
                                                float* __restrict__ dst, int n4) {
    int i = blockIdx.x * 256 + threadIdx.x;
    if (i < n4) ((float4*)dst)[i] = ((const float4*)in)[i];
}

extern "C" void kernel_launch(void* const* d_in, const int* in_sizes, int n_in,
                              void* d_out, int out_size, void* d_ws, size_t ws_size,
                              hipStream_t stream) {
    const float* q  = (const float*)d_in[0];
    const float* k  = (const float*)d_in[1];
    const float* W1 = (const float*)d_in[2];
    const float* W2 = (const float*)d_in[3];
    float* out = (float*)d_out;

    // ws: W1b | W2b | QK  (17.3 MB)
    ushort* W1b = (ushort*)d_ws;
    ushort* W2b = W1b + 131072;
    ushort* QK  = W2b + 131072;                 // [32768][256] bf16

    // H scratch inside d_out's weights region (overwritten by scores_softmax later)
    ushort* H = (ushort*)d_out;                 // [32768][512] bf16, 33.5 MB

    prep_w<<<512, 256, 0, stream>>>(W1, W2, W1b, W2b);
    conv1_fused<<<512, 512, 0, stream>>>(q, k, W1b, H);
    conv2_norm<<<256, 512, 0, stream>>>(H, W2b, QK);
    scores_softmax<<<512, 512, 0, stream>>>(QK, out);
    copy_key<<<4096, 256, 0, stream>>>(k, out + (size_t)B_ * N_ * N_, (B_ * CIN * N_) / 4);
}